// Round 1
// baseline (499.769 us; speedup 1.0000x reference)
//
#include <hip/hip_runtime.h>
#include <math.h>

#define N_INPC 3
#define N_HID 64
#define N_OUTC 10
#define SEQ_LEN 8
#define N_ROLL 16
#define DT 0.042f
#define GAMMA 2.7f
#define EPSC 4.7f
#define HH 12
#define WW 10
#define NPIX 120
#define BATCH 16
#define NC 128           // 2*N_HID state channels (order: [hz(64), hy(64)])
#define NK 1152          // NC * 9

// ---------------------------------------------------------------------------
// Transpose pw_w[o][c][i][j][p] (p innermost, stride-120 per k) into
// Wt[p][k][o] so per-pixel weight staging is fully coalesced.
// k = c*9 + (i*3+j), matching the s-patch ordering.
// grid = 1152 (one k per block), block = 256.
__global__ __launch_bounds__(256) void transpose_w_kernel(
    const float* __restrict__ pw_w, float* __restrict__ Wt) {
  __shared__ float t[64][121];
  const int k = blockIdx.x;
  const int tid = threadIdx.x;
  for (int e = tid; e < 64 * NPIX; e += 256) {
    int o = e / NPIX;
    int pp = e - o * NPIX;
    t[o][pp] = pw_w[(o * NK + k) * NPIX + pp];  // coalesced rows of 120
  }
  __syncthreads();
  for (int e = tid; e < 64 * NPIX; e += 256) {
    int o = e & 63;
    int pp = e >> 6;
    Wt[(pp * NK + k) * 64 + o] = t[o][pp];      // coalesced writes
  }
}

// ---------------------------------------------------------------------------
// Read-in conv: h[b][oc][p] over 24 in-channels, 3x3, EDGE padding.
// State layout S[b][c][p]: c in [0,64) = hz, [64,128) = hy  (concat([hz,hy])).
// hy = h[:, :64]  -> S channel 64+oc ; hz = h[:, 64:] -> S channel oc-64.
__global__ __launch_bounds__(256) void readin_kernel(
    const float* __restrict__ x, const float* __restrict__ rw,
    const float* __restrict__ rb, float* __restrict__ S) {
  const int n = blockIdx.x * 256 + threadIdx.x;
  if (n >= BATCH * NC * NPIX) return;
  const int p = n % NPIX;
  const int oc = (n / NPIX) & 127;
  const int b = n / (NPIX * NC);
  const int ph = p / WW, pw_ = p % WW;
  float acc = rb[oc];
  for (int ch = 0; ch < SEQ_LEN * N_INPC; ++ch) {
    const int tt = ch / N_INPC, ic = ch % N_INPC;
    const float* xb = x + (((tt * BATCH + b) * N_INPC + ic) * HH) * WW;
    const float* wb = rw + (oc * (SEQ_LEN * N_INPC) + ch) * 9;
#pragma unroll
    for (int di = 0; di < 3; ++di) {
      int ih = ph + di - 1;
      ih = ih < 0 ? 0 : (ih > HH - 1 ? HH - 1 : ih);
#pragma unroll
      for (int dj = 0; dj < 3; ++dj) {
        int iw = pw_ + dj - 1;
        iw = iw < 0 ? 0 : (iw > WW - 1 ? WW - 1 : iw);
        acc += xb[ih * WW + iw] * wb[di * 3 + dj];
      }
    }
  }
  const int sc = (oc < 64) ? (64 + oc) : (oc - 64);
  S[(b * NC + sc) * NPIX + p] = acc;
}

// ---------------------------------------------------------------------------
// One rollout step. WG per pixel (grid=120), 512 threads = 8 waves.
// Wave w owns K-slice [w*144, (w+1)*144), staged in wave-private LDS in
// chunks of 24 (no __syncthreads in the K loop). Each thread: 4b x 4o accs.
// Then LDS cross-wave reduce + fused tanh/state update (ping-pong Sin->Sout).
#define KC 24
__global__ __launch_bounds__(512) void step_kernel(
    const float* __restrict__ Wt, const float* __restrict__ Sin,
    float* __restrict__ Sout, const float* __restrict__ pwb) {
  __shared__ float lds[15360];  // 8 waves * (24*16 s + 24*64 w) = 61.4KB
  const int p = blockIdx.x;
  const int ph = p / WW, pw_ = p % WW;
  const int tid = threadIdx.x;
  const int wave = tid >> 6, lane = tid & 63;
  const int bq = lane >> 4;   // 4 batch-quads
  const int oq = lane & 15;   // 16 out-quads
  float acc[4][4] = {{0.f}};

  float* sbase = lds + wave * (KC * 80);       // 24*16 floats
  float* wbase = sbase + KC * 16;              // 24*64 floats
  float4* s4 = (float4*)sbase;
  float4* w4 = (float4*)wbase;
  const int kw0 = wave * 144;

  for (int chunk = 0; chunk < 6; ++chunk) {
    const int k0 = kw0 + chunk * KC;
    // stage s: 384 elems = 6 sweeps. s[kk][bb] = Sin[b][c][neighbor] (0-pad)
#pragma unroll
    for (int it = 0; it < 6; ++it) {
      const int e = lane + it * 64;
      const int kk = e >> 4, bb = e & 15;
      const int k = k0 + kk;
      const int c = k / 9;
      const int ij = k - c * 9;
      const int di = ij / 3;
      const int ih = ph + di - 1;
      const int iw = pw_ + (ij - di * 3) - 1;
      float v = 0.f;
      if (ih >= 0 && ih < HH && iw >= 0 && iw < WW)
        v = Sin[(bb * NC + c) * NPIX + ih * WW + iw];
      sbase[kk * 16 + bb] = v;
    }
    // stage w: 1536 floats = 384 float4 = 6 sweeps, fully coalesced
    const float4* src = (const float4*)(Wt + ((long)p * NK + k0) * 64);
#pragma unroll
    for (int it = 0; it < 6; ++it) {
      const int e = lane + it * 64;
      w4[e] = src[e];
    }
    // compute: 24 k x 16 FMA per thread
#pragma unroll
    for (int kk = 0; kk < KC; ++kk) {
      const float4 sv = s4[kk * 4 + bq];
      const float4 wv = w4[kk * 16 + oq];
      acc[0][0] += sv.x * wv.x; acc[0][1] += sv.x * wv.y;
      acc[0][2] += sv.x * wv.z; acc[0][3] += sv.x * wv.w;
      acc[1][0] += sv.y * wv.x; acc[1][1] += sv.y * wv.y;
      acc[1][2] += sv.y * wv.z; acc[1][3] += sv.y * wv.w;
      acc[2][0] += sv.z * wv.x; acc[2][1] += sv.z * wv.y;
      acc[2][2] += sv.z * wv.z; acc[2][3] += sv.z * wv.w;
      acc[3][0] += sv.w * wv.x; acc[3][1] += sv.w * wv.y;
      acc[3][2] += sv.w * wv.z; acc[3][3] += sv.w * wv.w;
    }
  }

  __syncthreads();
  // cross-wave reduce: red[(wave*64+lane)*20 + bi*4+oi], stride 20 (pad)
  float* red = lds;
  {
    float4* r = (float4*)(red + (wave * 64 + lane) * 20);
    r[0] = make_float4(acc[0][0], acc[0][1], acc[0][2], acc[0][3]);
    r[1] = make_float4(acc[1][0], acc[1][1], acc[1][2], acc[1][3]);
    r[2] = make_float4(acc[2][0], acc[2][1], acc[2][2], acc[2][3]);
    r[3] = make_float4(acc[3][0], acc[3][1], acc[3][2], acc[3][3]);
  }
  __syncthreads();
  for (int m = tid; m < 1024; m += 512) {
    const int lp = m >> 4, r = m & 15;
    float sum = 0.f;
#pragma unroll
    for (int w = 0; w < 8; ++w) sum += red[w * 1280 + lp * 20 + r];
    const int bi = r >> 2, oi = r & 3;
    const int b = (lp >> 4) * 4 + bi;
    const int o = (lp & 15) * 4 + oi;
    const float pre = sum + pwb[o * NPIX + p];
    const float hz = Sin[(b * NC + o) * NPIX + p];
    const float hy = Sin[(b * NC + 64 + o) * NPIX + p];
    const float hzn = hz + DT * (tanhf(pre) - GAMMA * hy - EPSC * hz);
    const float hyn = hy + DT * hzn;
    Sout[(b * NC + o) * NPIX + p] = hzn;
    Sout[(b * NC + 64 + o) * NPIX + p] = hyn;
  }
}

// ---------------------------------------------------------------------------
// Readout: out[b][o][p] = sum_c hy[b][c][p] * row[o][c] + rob[o]
__global__ __launch_bounds__(256) void readout_kernel(
    const float* __restrict__ S, const float* __restrict__ row,
    const float* __restrict__ rob, float* __restrict__ out) {
  const int n = blockIdx.x * 256 + threadIdx.x;
  if (n >= BATCH * N_OUTC * NPIX) return;
  const int p = n % NPIX;
  const int o = (n / NPIX) % N_OUTC;
  const int b = n / (NPIX * N_OUTC);
  float acc = rob[o];
#pragma unroll 8
  for (int c = 0; c < 64; ++c)
    acc += S[(b * NC + 64 + c) * NPIX + p] * row[o * 64 + c];
  out[n] = acc;
}

// ---------------------------------------------------------------------------
extern "C" void kernel_launch(void* const* d_in, const int* in_sizes, int n_in,
                              void* d_out, int out_size, void* d_ws, size_t ws_size,
                              hipStream_t stream) {
  const float* x         = (const float*)d_in[0];
  const float* readin_w  = (const float*)d_in[1];
  const float* readin_b  = (const float*)d_in[2];
  const float* pw_w      = (const float*)d_in[3];
  const float* pw_b      = (const float*)d_in[4];
  const float* readout_w = (const float*)d_in[5];
  const float* readout_b = (const float*)d_in[6];
  float* out = (float*)d_out;

  float* Wt = (float*)d_ws;                 // 8,847,360 floats (35.4 MB)
  float* SA = Wt + (size_t)NPIX * NK * 64;  // 245,760 floats
  float* SB = SA + (size_t)BATCH * NC * NPIX;

  transpose_w_kernel<<<NK, 256, 0, stream>>>(pw_w, Wt);
  readin_kernel<<<(BATCH * NC * NPIX + 255) / 256, 256, 0, stream>>>(
      x, readin_w, readin_b, SA);
  float* a = SA;
  float* b = SB;
  for (int s = 0; s < N_ROLL; ++s) {
    step_kernel<<<NPIX, 512, 0, stream>>>(Wt, a, b, pw_b);
    float* t = a; a = b; b = t;
  }
  readout_kernel<<<(BATCH * N_OUTC * NPIX + 255) / 256, 256, 0, stream>>>(
      a, readout_w, readout_b, out);
}

// Round 2
// 212.421 us; speedup vs baseline: 2.3527x; 2.3527x over previous
//
#include <hip/hip_runtime.h>
#include <math.h>

#define N_INPC 3
#define N_HID 64
#define N_OUTC 10
#define SEQ_LEN 8
#define N_ROLL 16
#define DT 0.042f
#define GAMMA 2.7f
#define EPSC 4.7f
#define HH 12
#define WW 10
#define NPIX 120
#define BATCH 16
#define NC 128
#define NK 1152

typedef __attribute__((ext_vector_type(8))) short short8;
typedef __attribute__((ext_vector_type(4))) float f32x4;
typedef unsigned short ushort_t;

__device__ __forceinline__ ushort_t f2bf(float v) {
  union { float f; unsigned u; } x; x.f = v;
  unsigned r = x.u + 0x7fff + ((x.u >> 16) & 1);  // round-nearest-even
  return (ushort_t)(r >> 16);
}

// ---------------------------------------------------------------------------
// Pack pw_w[o_g][c][i][j][p] (fp32, p innermost) into bf16
// Wt[p][h][ot][ks][kg][o][j] where k' = ij*128 + c = ks*32 + kg*8 + j,
// o_g = h*32 + ot*16 + o. B-fragment for (p,h,ot,ks) is then a contiguous,
// coalesced 16B-per-lane global load.
// 1,105,920 output 16B-vectors; thread t: p = t%120 (read-coalesced).
__global__ __launch_bounds__(256) void transpose2_kernel(
    const float* __restrict__ pw_w, ushort_t* __restrict__ Wt) {
  const int t = blockIdx.x * 256 + threadIdx.x;
  if (t >= 120 * 9216) return;
  const int p = t % 120;
  const int rest = t / 120;                 // [0, 9216)
  const int o = rest & 15;
  const int kg = (rest >> 4) & 3;
  const int ks = (rest >> 6) % 36;
  const int hot = (rest >> 6) / 36;         // h*2 + ot
  const int o_g = (hot >> 1) * 32 + (hot & 1) * 16 + o;
  const int k0 = ks * 32 + kg * 8;
  ushort_t out8[8];
#pragma unroll
  for (int j = 0; j < 8; ++j) {
    const int kp = k0 + j;
    const int ij = kp >> 7;                 // neighbor index 0..8
    const int c = kp & 127;                 // state channel
    const float v = pw_w[((size_t)o_g * NK + c * 9 + ij) * NPIX + p];
    out8[j] = f2bf(v);
  }
  uint4 pack;
  pack.x = (unsigned)out8[0] | ((unsigned)out8[1] << 16);
  pack.y = (unsigned)out8[2] | ((unsigned)out8[3] << 16);
  pack.z = (unsigned)out8[4] | ((unsigned)out8[5] << 16);
  pack.w = (unsigned)out8[6] | ((unsigned)out8[7] << 16);
  *(uint4*)(Wt + ((size_t)p * 9216 + rest) * 8) = pack;
}

// ---------------------------------------------------------------------------
// Read-in conv (EDGE pad), writes fp32 master Sm and bf16 Sg, layout
// [pix][b][c]: c in [0,64) = hz, [64,128) = hy.
__global__ __launch_bounds__(256) void readin2_kernel(
    const float* __restrict__ x, const float* __restrict__ rw,
    const float* __restrict__ rb, float* __restrict__ Sm,
    ushort_t* __restrict__ Sg) {
  const int n = blockIdx.x * 256 + threadIdx.x;
  if (n >= BATCH * NC * NPIX) return;
  const int p = n % NPIX;
  const int oc = (n / NPIX) & 127;
  const int b = n / (NPIX * NC);
  const int ph = p / WW, pw_ = p % WW;
  float acc = rb[oc];
  for (int ch = 0; ch < SEQ_LEN * N_INPC; ++ch) {
    const int tt = ch / N_INPC, ic = ch % N_INPC;
    const float* xb = x + (((tt * BATCH + b) * N_INPC + ic) * HH) * WW;
    const float* wb = rw + (oc * (SEQ_LEN * N_INPC) + ch) * 9;
#pragma unroll
    for (int di = 0; di < 3; ++di) {
      int ih = ph + di - 1;
      ih = ih < 0 ? 0 : (ih > HH - 1 ? HH - 1 : ih);
#pragma unroll
      for (int dj = 0; dj < 3; ++dj) {
        int iw = pw_ + dj - 1;
        iw = iw < 0 ? 0 : (iw > WW - 1 ? WW - 1 : iw);
        acc += xb[ih * WW + iw] * wb[di * 3 + dj];
      }
    }
  }
  const int sc = (oc < 64) ? (64 + oc) : (oc - 64);
  const size_t idx = ((size_t)(p * BATCH + b)) * NC + sc;
  Sm[idx] = acc;
  Sg[idx] = f2bf(acc);
}

// ---------------------------------------------------------------------------
// One rollout step. WG = (pixel p, o-half h). 256 threads = 4 waves.
// wave w: ot = w&1 (16 o's), kq = w>>1 (18 of 36 k-slices).
// A (16b x 1152k' bf16 patch) staged in LDS with XOR swizzle; B-fragments
// loaded straight global->VGPR (coalesced by construction of Wt).
// C layout (verified): col(o) = lane&15, row(b) = (lane>>4)*4 + reg.
__global__ __launch_bounds__(256) void step2_kernel(
    const ushort_t* __restrict__ Wt, const ushort_t* __restrict__ Sg_cur,
    const float* __restrict__ Sm_cur, ushort_t* __restrict__ Sg_nxt,
    float* __restrict__ Sm_nxt, const float* __restrict__ pwb) {
  __shared__ short8 SA[2304];   // 36,864 B : [row=k'/8][16 b-slots swizzled]
  __shared__ f32x4 red[128];    //  2,048 B : partials from waves 2,3
  const int wg = blockIdx.x, p = wg >> 1, h = wg & 1;
  const int ph = p / WW, pw_ = p % WW;
  const int tid = threadIdx.x, wv = tid >> 6, l = tid & 63;

  // ---- A build: A[b][k'] = Sg[neighbor(q)][b][c], k' = q*128 + c, 0-pad
  {
    const int b = tid >> 4, m = tid & 15;     // m*8 = c0
    const int bm = b * NC + m * 8;
#pragma unroll
    for (int q = 0; q < 9; ++q) {
      const int ih = ph + q / 3 - 1, iw = pw_ + q % 3 - 1;
      short8 v = {0, 0, 0, 0, 0, 0, 0, 0};
      if ((unsigned)ih < (unsigned)HH && (unsigned)iw < (unsigned)WW)
        v = *(const short8*)(Sg_cur + (size_t)(ih * WW + iw) * (BATCH * NC) + bm);
      const int row = q * 16 + m;             // = k'/8
      SA[row * 16 + (b ^ m)] = v;             // swizzle: slot = b ^ (row&15)
    }
  }
  __syncthreads();

  // ---- MFMA: 18 k-slices per wave, one o-tile per wave
  const int ot = wv & 1, kq = wv >> 1;
  const int kg = l >> 4, c16 = l & 15;
  const short8* __restrict__ WB =
      (const short8*)Wt + ((size_t)((p * 2 + h) * 2 + ot)) * 2304 + kg * 16 + c16;
  f32x4 acc0 = {0.f, 0.f, 0.f, 0.f}, acc1 = {0.f, 0.f, 0.f, 0.f};
#pragma unroll
  for (int ii = 0; ii < 9; ++ii) {
    const int ks0 = kq * 18 + ii * 2;
    {
      const int row = ks0 * 4 + kg;
      short8 av = SA[row * 16 + (c16 ^ (row & 15))];
      short8 bv = WB[ks0 * 64];
      acc0 = __builtin_amdgcn_mfma_f32_16x16x32_bf16(av, bv, acc0, 0, 0, 0);
    }
    {
      const int row = (ks0 + 1) * 4 + kg;
      short8 av = SA[row * 16 + (c16 ^ (row & 15))];
      short8 bv = WB[(ks0 + 1) * 64];
      acc1 = __builtin_amdgcn_mfma_f32_16x16x32_bf16(av, bv, acc1, 0, 0, 0);
    }
  }
  f32x4 acc = acc0 + acc1;

  // ---- cross-wave k reduction: pairs (0,2) and (1,3)
  if (wv >= 2) red[(wv - 2) * 64 + l] = acc;
  __syncthreads();
  if (wv < 2) {
    f32x4 part = red[wv * 64 + l];
    acc += part;
    const int o_g = h * 32 + ot * 16 + c16;
    const float pb = pwb[o_g * NPIX + p];
    const int b0 = (l >> 4) * 4;
#pragma unroll
    for (int r = 0; r < 4; ++r) {
      const int b = b0 + r;
      const size_t iz = ((size_t)(p * BATCH + b)) * NC + o_g;
      const float hz = Sm_cur[iz], hy = Sm_cur[iz + 64];
      const float pre = acc[r] + pb;
      const float hzn = hz + DT * (tanhf(pre) - GAMMA * hy - EPSC * hz);
      const float hyn = hy + DT * hzn;
      Sm_nxt[iz] = hzn;
      Sm_nxt[iz + 64] = hyn;
      Sg_nxt[iz] = f2bf(hzn);
      Sg_nxt[iz + 64] = f2bf(hyn);
    }
  }
}

// ---------------------------------------------------------------------------
__global__ __launch_bounds__(256) void readout2_kernel(
    const float* __restrict__ Sm, const float* __restrict__ row,
    const float* __restrict__ rob, float* __restrict__ out) {
  const int n = blockIdx.x * 256 + threadIdx.x;
  if (n >= BATCH * N_OUTC * NPIX) return;
  const int p = n % NPIX;
  const int o = (n / NPIX) % N_OUTC;
  const int b = n / (NPIX * N_OUTC);
  float acc = rob[o];
  const float* hy = Sm + ((size_t)(p * BATCH + b)) * NC + 64;
#pragma unroll 8
  for (int c = 0; c < 64; ++c) acc += hy[c] * row[o * 64 + c];
  out[n] = acc;
}

// ---------------------------------------------------------------------------
extern "C" void kernel_launch(void* const* d_in, const int* in_sizes, int n_in,
                              void* d_out, int out_size, void* d_ws, size_t ws_size,
                              hipStream_t stream) {
  const float* x         = (const float*)d_in[0];
  const float* readin_w  = (const float*)d_in[1];
  const float* readin_b  = (const float*)d_in[2];
  const float* pw_w      = (const float*)d_in[3];
  const float* pw_b      = (const float*)d_in[4];
  const float* readout_w = (const float*)d_in[5];
  const float* readout_b = (const float*)d_in[6];
  float* out = (float*)d_out;

  ushort_t* Wt  = (ushort_t*)d_ws;              // 8,847,360 bf16 = 17.7 MB
  ushort_t* Sg0 = Wt + (size_t)120 * 9216 * 8;  // 245,760 bf16
  ushort_t* Sg1 = Sg0 + 245760;
  float*    Sm0 = (float*)(Sg1 + 245760);       // 245,760 f32 (16B-aligned)
  float*    Sm1 = Sm0 + 245760;

  transpose2_kernel<<<4320, 256, 0, stream>>>(pw_w, Wt);
  readin2_kernel<<<(BATCH * NC * NPIX + 255) / 256, 256, 0, stream>>>(
      x, readin_w, readin_b, Sm0, Sg0);

  ushort_t* gc = Sg0; float* mc = Sm0;
  ushort_t* gn = Sg1; float* mn = Sm1;
  for (int s = 0; s < N_ROLL; ++s) {
    step2_kernel<<<NPIX * 2, 256, 0, stream>>>(Wt, gc, mc, gn, mn, pw_b);
    ushort_t* tg = gc; gc = gn; gn = tg;
    float* tm = mc; mc = mn; mn = tm;
  }
  readout2_kernel<<<(BATCH * N_OUTC * NPIX + 255) / 256, 256, 0, stream>>>(
      mc, readout_w, readout_b, out);
}